// Round 1
// baseline (373.490 us; speedup 1.0000x reference)
//
#include <hip/hip_runtime.h>

#define BB 32
#define HH 1024
#define LL 128
#define TT 127
#define VV 32000
#define NT 255  // LL+TT

typedef __attribute__((ext_vector_type(8))) short bf16x8;
typedef __attribute__((ext_vector_type(4))) float f32x4;

static __device__ __forceinline__ short f2bf(float f) {
  unsigned u = __builtin_bit_cast(unsigned, f);
  u += 0x7fffu + ((u >> 16) & 1u);   // round-to-nearest-even
  return (short)(u >> 16);
}

static __device__ __forceinline__ bf16x8 load_cvt8(const float* __restrict__ p) {
  f32x4 a = *(const f32x4*)p;
  f32x4 b = *(const f32x4*)(p + 4);
  bf16x8 r;
  r[0]=f2bf(a[0]); r[1]=f2bf(a[1]); r[2]=f2bf(a[2]); r[3]=f2bf(a[3]);
  r[4]=f2bf(b[0]); r[5]=f2bf(b[1]); r[6]=f2bf(b[2]); r[7]=f2bf(b[3]);
  return r;
}

static __device__ __forceinline__ bf16x8 load_add_cvt8(const float* __restrict__ p,
                                                       const float* __restrict__ q) {
  f32x4 a = *(const f32x4*)p, a2 = *(const f32x4*)(p + 4);
  f32x4 b = *(const f32x4*)q, b2 = *(const f32x4*)(q + 4);
  bf16x8 r;
  r[0]=f2bf(a[0]+b[0]); r[1]=f2bf(a[1]+b[1]); r[2]=f2bf(a[2]+b[2]); r[3]=f2bf(a[3]+b[3]);
  r[4]=f2bf(a2[0]+b2[0]); r[5]=f2bf(a2[1]+b2[1]); r[6]=f2bf(a2[2]+b2[2]); r[7]=f2bf(a2[3]+b2[3]);
  return r;
}

// ---------------------------------------------------------------------------
// 1) gates partials: compact rows {i:0..1023, g:1024..2047, o:2048..3071}
//    (f-gate skipped: c0 == 0). K split in 4: ks0/1 = W_ih x emb, ks2/3 = W_hh x (lh+th)
//    pgates[ks][3072][32]
// ---------------------------------------------------------------------------
__global__ __launch_bounds__(64) void k_gates(
    const int* __restrict__ wi, const float* __restrict__ lh,
    const float* __restrict__ th, const float* __restrict__ emb,
    const float* __restrict__ W_ih, const float* __restrict__ W_hh,
    float* __restrict__ pgates)
{
  int lane = threadIdx.x;
  int tile = blockIdx.x >> 2;     // 0..191
  int ks   = blockIdx.x & 3;
  int al = lane & 15, ah = lane >> 4;
  int cg = tile * 16 + al;
  int g  = (cg < 1024) ? cg : cg + 1024;
  const float* W = (ks < 2) ? W_ih : W_hh;
  int kbase = (ks & 1) * 512;
  const float* Arow = W + (size_t)g * HH + kbase + ah * 8;
  int b_lo = al, b_hi = al + 16;
  f32x4 acc_lo = {0.f,0.f,0.f,0.f}, acc_hi = {0.f,0.f,0.f,0.f};

  if (ks < 2) {
    const float* e_lo = emb + (size_t)wi[b_lo] * HH + kbase + ah * 8;
    const float* e_hi = emb + (size_t)wi[b_hi] * HH + kbase + ah * 8;
    #pragma unroll 4
    for (int kk = 0; kk < 16; ++kk) {
      bf16x8 a  = load_cvt8(Arow + kk * 32);
      bf16x8 bl = load_cvt8(e_lo + kk * 32);
      bf16x8 bh = load_cvt8(e_hi + kk * 32);
      acc_lo = __builtin_amdgcn_mfma_f32_16x16x32_bf16(a, bl, acc_lo, 0, 0, 0);
      acc_hi = __builtin_amdgcn_mfma_f32_16x16x32_bf16(a, bh, acc_hi, 0, 0, 0);
    }
  } else {
    const float* p_lo = lh + b_lo * HH + kbase + ah * 8;
    const float* q_lo = th + b_lo * HH + kbase + ah * 8;
    const float* p_hi = lh + b_hi * HH + kbase + ah * 8;
    const float* q_hi = th + b_hi * HH + kbase + ah * 8;
    #pragma unroll 4
    for (int kk = 0; kk < 16; ++kk) {
      bf16x8 a  = load_cvt8(Arow + kk * 32);
      bf16x8 bl = load_add_cvt8(p_lo + kk * 32, q_lo + kk * 32);
      bf16x8 bh = load_add_cvt8(p_hi + kk * 32, q_hi + kk * 32);
      acc_lo = __builtin_amdgcn_mfma_f32_16x16x32_bf16(a, bl, acc_lo, 0, 0, 0);
      acc_hi = __builtin_amdgcn_mfma_f32_16x16x32_bf16(a, bh, acc_hi, 0, 0, 0);
    }
  }
  float* outp = pgates + ((size_t)ks * 3072 + tile * 16) * 32;
  #pragma unroll
  for (int j = 0; j < 4; ++j) {
    int row = ah * 4 + j;
    outp[row * 32 + al]      = acc_lo[j];
    outp[row * 32 + al + 16] = acc_hi[j];
  }
}

// ---------------------------------------------------------------------------
// 2) LSTM cell: reduce partials, biases, nonlinearities, begin-select -> cur
// ---------------------------------------------------------------------------
__global__ __launch_bounds__(256) void k_cell(
    const float* __restrict__ pgates, const float* __restrict__ b_ih,
    const float* __restrict__ b_hh, const int* __restrict__ wi,
    const float* __restrict__ lh, float* __restrict__ cur_ws,
    float* __restrict__ out_cur)
{
  __shared__ int s_begin;
  if (threadIdx.x == 0) {
    int s = 0;
    #pragma unroll
    for (int i = 0; i < BB; ++i) s += wi[i];
    s_begin = (s == 0);
  }
  __syncthreads();
  int b = threadIdx.x & 31;
  int h = blockIdx.x * 8 + (threadIdx.x >> 5);
  float iv = 0.f, gv = 0.f, ov = 0.f;
  #pragma unroll
  for (int ks = 0; ks < 4; ++ks) {
    const float* p = pgates + (size_t)ks * 3072 * 32;
    iv += p[(size_t)h * 32 + b];
    gv += p[(size_t)(1024 + h) * 32 + b];
    ov += p[(size_t)(2048 + h) * 32 + b];
  }
  iv += b_ih[h] + b_hh[h];
  gv += b_ih[2048 + h] + b_hh[2048 + h];
  ov += b_ih[3072 + h] + b_hh[3072 + h];
  float ig = 1.f / (1.f + __expf(-iv));
  float og = 1.f / (1.f + __expf(-ov));
  float c1 = ig * tanhf(gv);
  float h1 = og * tanhf(c1);
  float c  = s_begin ? lh[b * HH + h] : h1;
  cur_ws[b * HH + h] = c;
  out_cur[b * HH + h] = c;
}

// ---------------------------------------------------------------------------
// 3) attention scores: one wave per (b, t); masked positions skip the dot
// ---------------------------------------------------------------------------
__global__ __launch_bounds__(256) void k_scores(
    const float* __restrict__ cur, const float* __restrict__ seq,
    const float* __restrict__ tree, const int* __restrict__ numNode,
    float* __restrict__ scores)
{
  int lane = threadIdx.x & 63;
  int gw = blockIdx.x * 4 + (threadIdx.x >> 6);
  if (gw >= BB * NT) return;
  int b = gw & 31, t = gw >> 5;
  int nn = numNode[b];
  int tl    = (t < LL) ? t : (t - LL);
  int limit = (t < LL) ? (nn + 1) : nn;
  if (tl >= limit) { if (lane == 0) scores[b * NT + t] = -1e30f; return; }
  const float* row = (t < LL) ? (seq + ((size_t)t * BB + b) * HH)
                              : (tree + ((size_t)(t - LL) * BB + b) * HH);
  const float* c = cur + b * HH;
  float acc = 0.f;
  #pragma unroll
  for (int ch = 0; ch < 4; ++ch) {
    int k = ch * 256 + lane * 4;
    f32x4 e = *(const f32x4*)(row + k);
    f32x4 q = *(const f32x4*)(c + k);
    acc += e[0]*q[0] + e[1]*q[1] + e[2]*q[2] + e[3]*q[3];
  }
  #pragma unroll
  for (int off = 32; off; off >>= 1) acc += __shfl_xor(acc, off);
  if (lane == 0) scores[b * NT + t] = acc;
}

// ---------------------------------------------------------------------------
// 4) softmax over 255 (in-block, redundant per h-chunk) + context accumulate
// ---------------------------------------------------------------------------
__global__ __launch_bounds__(256) void k_context(
    const float* __restrict__ scores, const float* __restrict__ seq,
    const float* __restrict__ tree, const int* __restrict__ numNode,
    float* __restrict__ ctx_ws, float* __restrict__ out_ctx)
{
  int b  = blockIdx.x >> 2;
  int hc = blockIdx.x & 3;
  int tid = threadIdx.x;
  __shared__ float w[256];
  __shared__ float red[4];
  float s = (tid < NT) ? scores[b * NT + tid] : -1e30f;
  float m = s;
  #pragma unroll
  for (int off = 32; off; off >>= 1) m = fmaxf(m, __shfl_xor(m, off));
  if ((tid & 63) == 0) red[tid >> 6] = m;
  __syncthreads();
  m = fmaxf(fmaxf(red[0], red[1]), fmaxf(red[2], red[3]));
  float e = (tid < NT) ? __expf(s - m) : 0.f;
  float z = e;
  #pragma unroll
  for (int off = 32; off; off >>= 1) z += __shfl_xor(z, off);
  __syncthreads();
  if ((tid & 63) == 0) red[tid >> 6] = z;
  __syncthreads();
  z = red[0] + red[1] + red[2] + red[3];
  w[tid] = e / z;
  __syncthreads();

  int h = hc * 256 + tid;
  int nn = numNode[b];
  int nl = nn + 1;
  float acc = 0.f;
  #pragma unroll 4
  for (int t = 0; t < nl; ++t) acc += w[t] * seq[((size_t)t * BB + b) * HH + h];
  #pragma unroll 4
  for (int t = 0; t < nn; ++t) acc += w[LL + t] * tree[((size_t)t * BB + b) * HH + h];
  ctx_ws[b * HH + h] = acc;
  out_ctx[b * HH + h] = acc;
}

// ---------------------------------------------------------------------------
// 5) comb partials: M=1024, K=2048 ([cur | ctx]), K-split 4 -> pcomb[4][1024][32]
// ---------------------------------------------------------------------------
__global__ __launch_bounds__(64) void k_comb(
    const float* __restrict__ W_comb, const float* __restrict__ cur,
    const float* __restrict__ ctx, float* __restrict__ pcomb)
{
  int lane = threadIdx.x;
  int tile = blockIdx.x >> 2;   // 0..63
  int ks   = blockIdx.x & 3;
  int al = lane & 15, ah = lane >> 4;
  int m = tile * 16 + al;
  int kbase = ks * 512;
  const float* Arow = W_comb + (size_t)m * 2048 + kbase + ah * 8;
  const float* X = (ks < 2) ? cur : ctx;
  int xkb = kbase & 1023;
  const float* xlo = X + al * HH + xkb + ah * 8;
  const float* xhi = X + (al + 16) * HH + xkb + ah * 8;
  f32x4 acc_lo = {0.f,0.f,0.f,0.f}, acc_hi = {0.f,0.f,0.f,0.f};
  #pragma unroll 4
  for (int kk = 0; kk < 16; ++kk) {
    bf16x8 a  = load_cvt8(Arow + kk * 32);
    bf16x8 bl = load_cvt8(xlo + kk * 32);
    bf16x8 bh = load_cvt8(xhi + kk * 32);
    acc_lo = __builtin_amdgcn_mfma_f32_16x16x32_bf16(a, bl, acc_lo, 0, 0, 0);
    acc_hi = __builtin_amdgcn_mfma_f32_16x16x32_bf16(a, bh, acc_hi, 0, 0, 0);
  }
  float* outp = pcomb + ((size_t)ks * 1024 + tile * 16) * 32;
  #pragma unroll
  for (int j = 0; j < 4; ++j) {
    int row = ah * 4 + j;
    outp[row * 32 + al]      = acc_lo[j];
    outp[row * 32 + al + 16] = acc_hi[j];
  }
}

// ---------------------------------------------------------------------------
// 6) comb reduce + bias + tanh -> tanh_h (f32 out) + bf16 copy for W_out GEMM
// ---------------------------------------------------------------------------
__global__ __launch_bounds__(256) void k_combred(
    const float* __restrict__ pcomb, const float* __restrict__ b_comb,
    float* __restrict__ out_th, unsigned short* __restrict__ thb)
{
  int b = threadIdx.x & 31;
  int m = blockIdx.x * 8 + (threadIdx.x >> 5);
  float v = 0.f;
  #pragma unroll
  for (int ks = 0; ks < 4; ++ks) v += pcomb[((size_t)ks * 1024 + m) * 32 + b];
  v = tanhf(v + b_comb[m]);
  out_th[b * HH + m] = v;
  thb[b * HH + m] = (unsigned short)f2bf(v);
}

// ---------------------------------------------------------------------------
// 7) out_vec = tanh_h @ W_out.T  (bias skipped: cancels in axis-0 softmax)
//    one wave per 16 vocab rows; store transposed vt[v][b]
// ---------------------------------------------------------------------------
__global__ __launch_bounds__(64) void k_wout(
    const float* __restrict__ W_out, const unsigned short* __restrict__ thb,
    float* __restrict__ vt)
{
  int lane = threadIdx.x;
  int tile = blockIdx.x;          // 0..1999
  int al = lane & 15, ah = lane >> 4;
  size_t row = (size_t)tile * 16 + al;
  const float* Arow = W_out + row * HH + ah * 8;
  const unsigned short* blo = thb + al * HH + ah * 8;
  const unsigned short* bhi = thb + (al + 16) * HH + ah * 8;
  f32x4 acc_lo = {0.f,0.f,0.f,0.f}, acc_hi = {0.f,0.f,0.f,0.f};
  #pragma unroll 4
  for (int kk = 0; kk < 32; ++kk) {
    bf16x8 a  = load_cvt8(Arow + kk * 32);
    bf16x8 bl = *(const bf16x8*)(blo + kk * 32);
    bf16x8 bh = *(const bf16x8*)(bhi + kk * 32);
    acc_lo = __builtin_amdgcn_mfma_f32_16x16x32_bf16(a, bl, acc_lo, 0, 0, 0);
    acc_hi = __builtin_amdgcn_mfma_f32_16x16x32_bf16(a, bh, acc_hi, 0, 0, 0);
  }
  float* outp = vt + (size_t)tile * 16 * 32;
  #pragma unroll
  for (int j = 0; j < 4; ++j) {
    int r = ah * 4 + j;
    outp[r * 32 + al]      = acc_lo[j];
    outp[r * 32 + al + 16] = acc_hi[j];
  }
}

// ---------------------------------------------------------------------------
// 8) softmax over batch (axis 0): thread per vocab entry
// ---------------------------------------------------------------------------
__global__ __launch_bounds__(256) void k_psoftmax(
    const float* __restrict__ vt, float* __restrict__ prob)
{
  int v = blockIdx.x * 256 + threadIdx.x;
  const float* r = vt + (size_t)v * 32;
  float x[32];
  #pragma unroll
  for (int i = 0; i < 8; ++i) {
    f32x4 t = *(const f32x4*)(r + i * 4);
    x[i*4+0] = t[0]; x[i*4+1] = t[1]; x[i*4+2] = t[2]; x[i*4+3] = t[3];
  }
  float m = x[0];
  #pragma unroll
  for (int i = 1; i < 32; ++i) m = fmaxf(m, x[i]);
  float z = 0.f;
  #pragma unroll
  for (int i = 0; i < 32; ++i) { x[i] = __expf(x[i] - m); z += x[i]; }
  float inv = 1.f / z;
  #pragma unroll
  for (int i = 0; i < 32; ++i) prob[(size_t)i * VV + v] = x[i] * inv;
}

// ---------------------------------------------------------------------------
extern "C" void kernel_launch(void* const* d_in, const int* in_sizes, int n_in,
                              void* d_out, int out_size, void* d_ws, size_t ws_size,
                              hipStream_t stream) {
  const int*   wi    = (const int*)d_in[0];
  const float* lh    = (const float*)d_in[1];
  const float* thid  = (const float*)d_in[2];
  const float* tree  = (const float*)d_in[3];
  const float* seq   = (const float*)d_in[4];
  const int*   nn    = (const int*)d_in[5];
  const float* emb   = (const float*)d_in[6];
  const float* Wih   = (const float*)d_in[7];
  const float* Whh   = (const float*)d_in[8];
  const float* bih   = (const float*)d_in[9];
  const float* bhh   = (const float*)d_in[10];
  const float* Wcomb = (const float*)d_in[11];
  const float* bcomb = (const float*)d_in[12];
  const float* Wout  = (const float*)d_in[13];
  // d_in[14] = b_out: unused — per-v constant cancels in softmax over batch axis

  float* out = (float*)d_out;
  float* ws  = (float*)d_ws;
  float* pgates = ws;                       // 4*3072*32 = 393216
  float* pcomb  = ws + 393216;              // 4*1024*32 = 131072
  float* cur    = ws + 524288;              // 32768
  float* ctx    = ws + 557056;              // 32768
  float* scores = ws + 589824;              // 8160 (pad 8192)
  unsigned short* thb = (unsigned short*)(ws + 598016);  // 32768 bf16 = 16384 fl
  float* vt     = ws + 614400;              // 32000*32 = 1024000

  float* o_prob = out;                      // (B,V)
  float* o_cur  = out + 1024000;            // (B,H)
  float* o_th   = out + 1056768;            // (B,H)
  float* o_ctx  = out + 1089536;            // (B,H)

  k_gates   <<<dim3(768),  dim3(64),  0, stream>>>(wi, lh, thid, emb, Wih, Whh, pgates);
  k_cell    <<<dim3(128),  dim3(256), 0, stream>>>(pgates, bih, bhh, wi, lh, cur, o_cur);
  k_scores  <<<dim3(2040), dim3(256), 0, stream>>>(cur, seq, tree, nn, scores);
  k_context <<<dim3(128),  dim3(256), 0, stream>>>(scores, seq, tree, nn, ctx, o_ctx);
  k_comb    <<<dim3(256),  dim3(64),  0, stream>>>(Wcomb, cur, ctx, pcomb);
  k_combred <<<dim3(128),  dim3(256), 0, stream>>>(pcomb, bcomb, o_th, thb);
  k_wout    <<<dim3(2000), dim3(64),  0, stream>>>(Wout, thb, vt);
  k_psoftmax<<<dim3(125),  dim3(256), 0, stream>>>(vt, o_prob);
}